// Round 3
// baseline (319.467 us; speedup 1.0000x reference)
//
#include <hip/hip_runtime.h>

#define NN 100000
#define NE 1600000
#define D 64
#define SCAN_B 256
#define NB_SCAN ((NN + SCAN_B - 1) / SCAN_B)   // 391

// ---------------- histogram (in-degree) ----------------

__global__ void k_hist(const int* __restrict__ dst, int* __restrict__ cnt, int e) {
    int i = (blockIdx.x * blockDim.x + threadIdx.x) * 4;
    if (i + 3 < e) {
        int4 d = *(const int4*)(dst + i);
        atomicAdd(&cnt[d.x], 1);
        atomicAdd(&cnt[d.y], 1);
        atomicAdd(&cnt[d.z], 1);
        atomicAdd(&cnt[d.w], 1);
    } else {
        for (; i < e; ++i) atomicAdd(&cnt[dst[i]], 1);
    }
}

// ---------------- 3-phase exclusive scan of cnt -> rowstart, cursor ----------------

__global__ void k_scan_block(const int* __restrict__ cnt, int* __restrict__ excl,
                             int* __restrict__ bsum, int n) {
    __shared__ int tmp[SCAN_B];
    int tid = threadIdx.x;
    int i = blockIdx.x * SCAN_B + tid;
    int v = (i < n) ? cnt[i] : 0;
    tmp[tid] = v;
    __syncthreads();
    for (int off = 1; off < SCAN_B; off <<= 1) {
        int t = (tid >= off) ? tmp[tid - off] : 0;
        __syncthreads();
        tmp[tid] += t;
        __syncthreads();
    }
    if (i < n) excl[i] = tmp[tid] - v;
    if (tid == SCAN_B - 1) bsum[blockIdx.x] = tmp[tid];
}

__global__ void k_scan_bsum(int* __restrict__ bsum, int nb) {
    __shared__ int tmp[512];
    int tid = threadIdx.x;
    int v = (tid < nb) ? bsum[tid] : 0;
    tmp[tid] = v;
    __syncthreads();
    for (int off = 1; off < 512; off <<= 1) {
        int t = (tid >= off) ? tmp[tid - off] : 0;
        __syncthreads();
        tmp[tid] += t;
        __syncthreads();
    }
    if (tid < nb) bsum[tid] = tmp[tid] - v;
}

__global__ void k_scan_add(int* __restrict__ excl, int* __restrict__ cursor,
                           const int* __restrict__ bsum, int n) {
    int i = blockIdx.x * blockDim.x + threadIdx.x;
    if (i < n) {
        int r = excl[i] + bsum[blockIdx.x];   // blockDim == SCAN_B
        excl[i] = r;
        cursor[i] = r;
    }
}

// ---------------- projection fused with dinv scaling: xw2 = (x @ W) * dinv ----------------
// block = 256 threads = 4 rows x 64 cols
__global__ void k_xw2(const float* __restrict__ x, const float* __restrict__ W,
                      const int* __restrict__ cnt, float* __restrict__ xw2, int n) {
    __shared__ float sW[D][D];
    __shared__ float sx[4][D];
    int col = threadIdx.x & 63;
    int r   = threadIdx.x >> 6;

    for (int i = threadIdx.x; i < D * D; i += 256)
        sW[i >> 6][i & 63] = W[i];

    int row = blockIdx.x * 4 + r;
    if (row < n) sx[r][col] = x[row * D + col];
    __syncthreads();
    if (row >= n) return;

    float acc = 0.f;
#pragma unroll
    for (int k = 0; k < D; ++k)
        acc += sx[r][k] * sW[k][col];

    float di = rsqrtf((float)cnt[row] + 1.0f);   // +1 = self-loop
    xw2[row * D + col] = acc * di;
}

// ---------------- CSR build: place src ids in dst order (4-B records) ----------------

__global__ void k_build(const int* __restrict__ src, const int* __restrict__ dst,
                        int* __restrict__ cursor, int* __restrict__ recs, int e) {
    int i = (blockIdx.x * blockDim.x + threadIdx.x) * 2;
    if (i + 1 < e) {
        int2 s = *(const int2*)(src + i);
        int2 d = *(const int2*)(dst + i);
        recs[atomicAdd(&cursor[d.x], 1)] = s.x;
        recs[atomicAdd(&cursor[d.y], 1)] = s.y;
    } else if (i < e) {
        recs[atomicAdd(&cursor[dst[i]], 1)] = src[i];
    }
}

// ---------------- gather-accumulate: one wave per node ----------------
// out[d] = dinv[d] * (xw2[d] + sum_{s in N(d)} xw2[s]) + b

__global__ void k_gather(const int* __restrict__ recs, const int* __restrict__ rowstart,
                         const int* __restrict__ cnt, const float* __restrict__ xw2,
                         const float* __restrict__ b, float* __restrict__ out, int n) {
    int wid  = (blockIdx.x * blockDim.x + threadIdx.x) >> 6;   // node id
    int lane = threadIdx.x & 63;                                // column
    if (wid >= n) return;

    int base = __builtin_amdgcn_readfirstlane(rowstart[wid]);
    int k    = __builtin_amdgcn_readfirstlane(cnt[wid]);

    float acc = xw2[(size_t)wid * D + lane];   // self-loop term (already dinv-scaled)

    int i = 0;
    for (; i + 4 <= k; i += 4) {
        int s0 = recs[base + i + 0];
        int s1 = recs[base + i + 1];
        int s2 = recs[base + i + 2];
        int s3 = recs[base + i + 3];
        acc += xw2[(size_t)s0 * D + lane];
        acc += xw2[(size_t)s1 * D + lane];
        acc += xw2[(size_t)s2 * D + lane];
        acc += xw2[(size_t)s3 * D + lane];
    }
    for (; i < k; ++i)
        acc += xw2[(size_t)recs[base + i] * D + lane];

    float di = rsqrtf((float)k + 1.0f);
    out[(size_t)wid * D + lane] = acc * di + b[lane];
}

extern "C" void kernel_launch(void* const* d_in, const int* in_sizes, int n_in,
                              void* d_out, int out_size, void* d_ws, size_t ws_size,
                              hipStream_t stream) {
    const float* x  = (const float*)d_in[0];
    const int*   ei = (const int*)d_in[1];   // [2, E]: src row then dst row (int32)
    const float* W  = (const float*)d_in[2];
    const float* b  = (const float*)d_in[3];
    float* out = (float*)d_out;

    // workspace layout (4-B elements)
    float* xw2      = (float*)d_ws;                      // N*D = 25.6 MB
    int*   cnt      = (int*)(xw2 + (size_t)NN * D);      // N
    int*   rowstart = cnt + NN;                          // N
    int*   cursor   = rowstart + NN;                     // N
    int*   bsum     = cursor + NN;                       // 512
    int*   recs     = bsum + 512;                        // E = 6.4 MB

    const int* src = ei;
    const int* dst = ei + NE;

    hipMemsetAsync(cnt, 0, (size_t)NN * sizeof(int), stream);

    k_hist      <<<(NE / 4 + 255) / 256, 256, 0, stream>>>(dst, cnt, NE);

    k_scan_block<<<NB_SCAN, SCAN_B, 0, stream>>>(cnt, rowstart, bsum, NN);
    k_scan_bsum <<<1, 512, 0, stream>>>(bsum, NB_SCAN);
    k_scan_add  <<<NB_SCAN, SCAN_B, 0, stream>>>(rowstart, cursor, bsum, NN);

    k_xw2       <<<(NN + 3) / 4, 256, 0, stream>>>(x, W, cnt, xw2, NN);
    k_build     <<<(NE / 2 + 255) / 256, 256, 0, stream>>>(src, dst, cursor, recs, NE);

    long long tot = (long long)NN * 64;
    k_gather    <<<(int)((tot + 255) / 256), 256, 0, stream>>>(recs, rowstart, cnt, xw2, b, out, NN);
}